// Round 1
// 503.514 us; speedup vs baseline: 1.0907x; 1.0907x over previous
//
#include <hip/hip_runtime.h>
#include <stdint.h>

// Problem constants (from reference)
#define HH 176
#define WW 200
#define BB 4
#define CIN 128
#define COUT 256
#define NPTS (4096 * 64)            // 262144 points
#define CELLS (BB * WW * HH)        // 140800 cells = 2200 * 64
#define FEAT_OUT_ELEMS ((size_t)NPTS * COUT)  // 67108864
#define CAP 32                      // max points/cell tracked (Poisson lambda~1.6 -> max ~12)
#define LDSW 260                    // 256 + 4 pad -> 2-way LDS banks on f32x4 stores (free)

typedef __attribute__((ext_vector_type(8))) short bf16x8;
typedef __attribute__((ext_vector_type(4))) float f32x4;

// ---------- bf16 helpers (RNE) ----------
__device__ __forceinline__ unsigned short f2bf(float f) {
    union { float f; unsigned int u; } c; c.f = f;
    unsigned int u = c.u;
    u += 0x7fffu + ((u >> 16) & 1u);
    return (unsigned short)(u >> 16);
}

// ---------- 1. build per-cell point lists (1 atomic per point) + index echo ----------
__global__ __launch_bounds__(256) void build_kernel(
    const int* __restrict__ idx, int* __restrict__ counts, int* __restrict__ plist,
    float* __restrict__ out_idx)
{
    int p = blockIdx.x * 256 + threadIdx.x;
    int b = idx[3 * p], x = idx[3 * p + 1], y = idx[3 * p + 2];
    // index echo (coalesced here; removed from the old gather kernel)
    out_idx[3 * p]     = (float)b;
    out_idx[3 * p + 1] = (float)x;
    out_idx[3 * p + 2] = (float)y;
    if ((unsigned)x < HH && (unsigned)y < WW) {
        int cell = (b * WW + y) * HH + x;
        int slot = atomicAdd(&counts[cell], 1);
        if (slot < CAP) plist[(size_t)cell * CAP + slot] = p;
    }
}

// ---------- 1b. zero output rows of invalid points (scatter only writes valid rows) ----------
__global__ __launch_bounds__(256) void zero_invalid_kernel(
    const int* __restrict__ idx, float* __restrict__ out_feats)
{
    int p = blockIdx.x * 4 + (threadIdx.x >> 6);
    int lane = threadIdx.x & 63;
    int x = idx[3 * p + 1], y = idx[3 * p + 2];
    if (!((unsigned)x < HH && (unsigned)y < WW)) {
        float4 z = { 0.0f, 0.0f, 0.0f, 0.0f };
        *(float4*)(out_feats + (size_t)p * COUT + lane * 4) = z;
    }
}

// ---------- 2. fused per-cell sum + layernorm -> bf16 ----------
// wave per cell, lane handles 2 channels
__global__ __launch_bounds__(256) void cell_kernel(
    const float* __restrict__ feats, const int* __restrict__ counts,
    const int* __restrict__ plist,
    const float* __restrict__ nw, const float* __restrict__ nb,
    unsigned short* __restrict__ normed)
{
    int cell = blockIdx.x * 4 + (threadIdx.x >> 6);
    int lane = threadIdx.x & 63;
    int n = counts[cell]; n = n < CAP ? n : CAP;
    const int* pl = plist + (size_t)cell * CAP;
    float a0 = 0.0f, a1 = 0.0f;
    for (int i = 0; i < n; ++i) {
        int pid = pl[i];
        float2 v = *(const float2*)(feats + (size_t)pid * CIN + lane * 2);
        a0 += v.x; a1 += v.y;
    }
    float s = a0 + a1;
    float ss = a0 * a0 + a1 * a1;
    #pragma unroll
    for (int m = 32; m >= 1; m >>= 1) {
        s  += __shfl_xor(s, m, 64);
        ss += __shfl_xor(ss, m, 64);
    }
    float mu  = s * (1.0f / 128.0f);
    float var = ss * (1.0f / 128.0f) - mu * mu;
    float inv = rsqrtf(var + 1e-5f);
    float w0 = nw[lane * 2], w1 = nw[lane * 2 + 1];
    float b0 = nb[lane * 2], b1 = nb[lane * 2 + 1];
    ushort2 st;
    st.x = f2bf((a0 - mu) * inv * w0 + b0);
    st.y = f2bf((a1 - mu) * inv * w1 + b1);
    *(ushort2*)(normed + (size_t)cell * CIN + lane * 2) = st;
}

// ---------- 3a. convert linear weight to bf16 ----------
__global__ __launch_bounds__(256) void wcvt_kernel(
    const float* __restrict__ lw, unsigned short* __restrict__ wb)
{
    int i = blockIdx.x * 256 + threadIdx.x;   // 32768 elems
    wb[i] = f2bf(lw[i]);
}

// ---------- 3b. fused MFMA GEMM + per-point scatter ----------
// block: 64 cells x 256 outputs; wave w: o-tiles 4w..4w+3 (16x16x32 bf16 MFMA).
// Per 16-cell sub-tile j: compute 16x256 f32 outputs, transpose via LDS,
// then write each listed point's 256-ch row as one coalesced 1 KB store.
// Eliminates the 72 MB dout write + 115 MB random gather read of the old pipeline.
__global__ __launch_bounds__(256) void gemm_scatter_kernel(
    const unsigned short* __restrict__ A,   // normed [CELLS][128] bf16
    const unsigned short* __restrict__ Wb,  // [256][128] bf16
    const int* __restrict__ counts,
    const int* __restrict__ plist,
    float* __restrict__ out)                // [NPTS][256] f32
{
    __shared__ float lds_out[16 * LDSW];    // 16 cells x 256 ch (padded)
    __shared__ int scnt[64];
    __shared__ int spid[64 * CAP];

    int n0 = blockIdx.x * 64;
    int tid = threadIdx.x;
    int w = tid >> 6;
    int lane = tid & 63;
    int l15 = lane & 15;
    int kgrp = (lane >> 4) * 8;
    int orow = (lane >> 4) * 4;

    // preload per-cell point lists into shared
    if (tid < 64) {
        int cnt = counts[n0 + tid]; cnt = cnt < CAP ? cnt : CAP;
        scnt[tid] = cnt;
        for (int s = 0; s < cnt; ++s)
            spid[tid * CAP + s] = plist[(size_t)(n0 + tid) * CAP + s];
    }

    // preload all W fragments (L2-hot, 64 KB total buffer)
    bf16x8 a[4][4];
    #pragma unroll
    for (int i = 0; i < 4; ++i)
        #pragma unroll
        for (int kk = 0; kk < 4; ++kk)
            a[i][kk] = *(const bf16x8*)(Wb + (size_t)(((w * 4 + i) * 16 + l15) * CIN) + kgrp + kk * 32);

    const unsigned short* bbase = A + (size_t)(n0 + l15) * CIN + kgrp;
    bf16x8 bcur[4];
    #pragma unroll
    for (int kk = 0; kk < 4; ++kk)
        bcur[kk] = *(const bf16x8*)(bbase + kk * 32);

    __syncthreads();  // scnt/spid ready

    #pragma unroll
    for (int j = 0; j < 4; ++j) {
        // prefetch next sub-tile's B fragments (hidden under MFMA + scatter)
        bf16x8 bnext[4];
        if (j < 3) {
            #pragma unroll
            for (int kk = 0; kk < 4; ++kk)
                bnext[kk] = *(const bf16x8*)(bbase + (size_t)(j + 1) * 16 * CIN + kk * 32);
        } else {
            #pragma unroll
            for (int kk = 0; kk < 4; ++kk) bnext[kk] = bcur[kk];
        }

        f32x4 acc[4];
        #pragma unroll
        for (int i = 0; i < 4; ++i) acc[i] = (f32x4){0.0f, 0.0f, 0.0f, 0.0f};
        #pragma unroll
        for (int kk = 0; kk < 4; ++kk)
            #pragma unroll
            for (int i = 0; i < 4; ++i)
                acc[i] = __builtin_amdgcn_mfma_f32_16x16x32_bf16(a[i][kk], bcur[kk], acc[i], 0, 0, 0);

        // C/D layout: col(cell-within-tile)=lane&15, row(o-within-tile)=(lane>>4)*4+reg
        #pragma unroll
        for (int i = 0; i < 4; ++i)
            *(f32x4*)(&lds_out[l15 * LDSW + (w * 4 + i) * 16 + orow]) = acc[i];

        __syncthreads();

        // scatter: one coalesced 1 KB row store per listed point
        int cbase = j * 16;
        for (int c = 0; c < 16; ++c) {
            int cnt = scnt[cbase + c];
            const float* row = &lds_out[c * LDSW];
            for (int t = 0; t < cnt; ++t) {
                int pid = spid[(cbase + c) * CAP + t];
                out[(size_t)pid * COUT + tid] = row[tid];
            }
        }

        __syncthreads();

        #pragma unroll
        for (int kk = 0; kk < 4; ++kk) bcur[kk] = bnext[kk];
    }
}

extern "C" void kernel_launch(void* const* d_in, const int* in_sizes, int n_in,
                              void* d_out, int out_size, void* d_ws, size_t ws_size,
                              hipStream_t stream)
{
    const float* feats = (const float*)d_in[0];
    const int*   idx   = (const int*)d_in[1];
    const float* nw    = (const float*)d_in[2];
    const float* nb    = (const float*)d_in[3];
    const float* lw    = (const float*)d_in[4];
    float* out = (float*)d_out;

    char* ws = (char*)d_ws;
    int* counts = (int*)ws;                                        // 0.56 MB
    int* plist  = (int*)(ws + (1u << 20));                         // 18 MB
    unsigned short* normed = (unsigned short*)(ws + (20u << 20));  // 36 MB bf16
    unsigned short* wb     = (unsigned short*)(ws + (60u << 20));  // 64 KB bf16

    hipMemsetAsync(counts, 0, (size_t)CELLS * 4, stream);
    zero_invalid_kernel<<<NPTS / 4, 256, 0, stream>>>(idx, out);
    build_kernel<<<NPTS / 256, 256, 0, stream>>>(idx, counts, plist, out + FEAT_OUT_ELEMS);
    cell_kernel<<<CELLS / 4, 256, 0, stream>>>(feats, counts, plist, nw, nb, normed);
    wcvt_kernel<<<COUT * CIN / 256, 256, 0, stream>>>(lw, wb);
    gemm_scatter_kernel<<<CELLS / 64, 256, 0, stream>>>(normed, wb, counts, plist, out);
}

// Round 2
// 478.232 us; speedup vs baseline: 1.1484x; 1.0529x over previous
//
#include <hip/hip_runtime.h>
#include <stdint.h>

// Problem constants (from reference)
#define HH 176
#define WW 200
#define BB 4
#define CIN 128
#define COUT 256
#define NPTS (4096 * 64)            // 262144 points
#define CELLS (BB * WW * HH)        // 140800 cells = 2200 * 64
#define FEAT_OUT_ELEMS ((size_t)NPTS * COUT)  // 67108864
#define CAP 32                      // max points/cell tracked (Poisson lambda~1.6 -> max ~12)
#define LDSW16 260                  // ushort stride (520 B = 130 words): transpose-write 2-way banks (free)
#define FLATCAP 1024                // block flat point list (avg ~100, max ~150 across 2200 blocks)

typedef __attribute__((ext_vector_type(8))) short bf16x8;
typedef __attribute__((ext_vector_type(4))) float f32x4;

// ---------- bf16 helpers (RNE) ----------
__device__ __forceinline__ unsigned short f2bf(float f) {
    union { float f; unsigned int u; } c; c.f = f;
    unsigned int u = c.u;
    u += 0x7fffu + ((u >> 16) & 1u);
    return (unsigned short)(u >> 16);
}
__device__ __forceinline__ float bf2f(unsigned int h16) {
    union { unsigned int u; float f; } c; c.u = h16 << 16;
    return c.f;
}

// ---------- 1. build: per-cell lists + index echo + zero invalid output rows ----------
__global__ __launch_bounds__(256) void build_kernel(
    const int* __restrict__ idx, int* __restrict__ counts, int* __restrict__ plist,
    float* __restrict__ out_idx, float* __restrict__ out_feats)
{
    __shared__ unsigned char validf[256];
    int tid = threadIdx.x;
    int p0 = blockIdx.x * 256;
    int p = p0 + tid;
    int b = idx[3 * p], x = idx[3 * p + 1], y = idx[3 * p + 2];
    out_idx[3 * p]     = (float)b;
    out_idx[3 * p + 1] = (float)x;
    out_idx[3 * p + 2] = (float)y;
    bool valid = ((unsigned)x < HH && (unsigned)y < WW);
    validf[tid] = valid ? 1 : 0;
    if (valid) {
        int cell = (b * WW + y) * HH + x;
        int slot = atomicAdd(&counts[cell], 1);
        if (slot < CAP) plist[(size_t)cell * CAP + slot] = p;
    }
    __syncthreads();
    // cooperatively zero the 256-ch output rows of this block's invalid points
    int w = tid >> 6, lane = tid & 63;
    float4 z = { 0.0f, 0.0f, 0.0f, 0.0f };
    for (int v = w; v < 256; v += 4)
        if (!validf[v])
            *(float4*)(out_feats + (size_t)(p0 + v) * COUT + lane * 4) = z;
}

// ---------- 2. fused per-cell sum + layernorm -> bf16 ----------
// wave per cell, lane handles 2 channels
__global__ __launch_bounds__(256) void cell_kernel(
    const float* __restrict__ feats, const int* __restrict__ counts,
    const int* __restrict__ plist,
    const float* __restrict__ nw, const float* __restrict__ nb,
    unsigned short* __restrict__ normed)
{
    int cell = blockIdx.x * 4 + (threadIdx.x >> 6);
    int lane = threadIdx.x & 63;
    int n = counts[cell]; n = n < CAP ? n : CAP;
    const int* pl = plist + (size_t)cell * CAP;
    float a0 = 0.0f, a1 = 0.0f;
    for (int i = 0; i < n; ++i) {
        int pid = pl[i];
        float2 v = *(const float2*)(feats + (size_t)pid * CIN + lane * 2);
        a0 += v.x; a1 += v.y;
    }
    float s = a0 + a1;
    float ss = a0 * a0 + a1 * a1;
    #pragma unroll
    for (int m = 32; m >= 1; m >>= 1) {
        s  += __shfl_xor(s, m, 64);
        ss += __shfl_xor(ss, m, 64);
    }
    float mu  = s * (1.0f / 128.0f);
    float var = ss * (1.0f / 128.0f) - mu * mu;
    float inv = rsqrtf(var + 1e-5f);
    float w0 = nw[lane * 2], w1 = nw[lane * 2 + 1];
    float b0 = nb[lane * 2], b1 = nb[lane * 2 + 1];
    ushort2 st;
    st.x = f2bf((a0 - mu) * inv * w0 + b0);
    st.y = f2bf((a1 - mu) * inv * w1 + b1);
    *(ushort2*)(normed + (size_t)cell * CIN + lane * 2) = st;
}

// ---------- 3a. convert linear weight to bf16 ----------
__global__ __launch_bounds__(256) void wcvt_kernel(
    const float* __restrict__ lw, unsigned short* __restrict__ wb)
{
    int i = blockIdx.x * 256 + threadIdx.x;   // 32768 elems
    wb[i] = f2bf(lw[i]);
}

// ---------- 3b. fused MFMA GEMM + per-point scatter (v2) ----------
// block: 64 cells x 256 outputs; wave w owns o-tiles 4w..4w+3 (16x16x32 bf16 MFMA).
// Whole 64x256 tile transposed into bf16 LDS (33 KB, disjoint per wave -> no inter-phase
// barriers). Block-level flat point list -> single scatter loop, one float4 row-quarter
// store per wave per iteration. LDS 38 KB -> 4 blocks/CU (vs 75 KB -> 2 before).
__global__ __launch_bounds__(256) void gemm_scatter_kernel(
    const unsigned short* __restrict__ A,   // normed [CELLS][128] bf16
    const unsigned short* __restrict__ Wb,  // [256][128] bf16
    const int* __restrict__ counts,
    const int* __restrict__ plist,
    float* __restrict__ out)                // [NPTS][256] f32
{
    __shared__ unsigned short lds16[64 * LDSW16];   // 33,280 B
    __shared__ int fpid[FLATCAP];                   // 4 KB
    __shared__ unsigned char fcell[FLATCAP];        // 1 KB
    __shared__ int nflat;

    int n0 = blockIdx.x * 64;
    int tid = threadIdx.x;
    int w = tid >> 6;
    int lane = tid & 63;
    int l15 = lane & 15;
    int kgrp = (lane >> 4) * 8;
    int orow = (lane >> 4) * 4;

    if (tid == 0) nflat = 0;
    __syncthreads();

    // build the block's flat (pid, cell) list
    if (tid < 64) {
        int cnt = counts[n0 + tid]; cnt = cnt < CAP ? cnt : CAP;
        if (cnt > 0) {
            int base = atomicAdd(&nflat, cnt);
            for (int s = 0; s < cnt; ++s) {
                int pos = base + s;
                if (pos < FLATCAP) {
                    fpid[pos] = plist[(size_t)(n0 + tid) * CAP + s];
                    fcell[pos] = (unsigned char)tid;
                }
            }
        }
    }

    // preload all W fragments (hot in L2/L3: 64 KB buffer)
    bf16x8 a[4][4];
    #pragma unroll
    for (int i = 0; i < 4; ++i)
        #pragma unroll
        for (int kk = 0; kk < 4; ++kk)
            a[i][kk] = *(const bf16x8*)(Wb + (size_t)(((w * 4 + i) * 16 + l15) * CIN) + kgrp + kk * 32);

    const unsigned short* bbase = A + (size_t)(n0 + l15) * CIN + kgrp;

    // 4 cell sub-tiles; each wave writes a disjoint 64-ch column band of lds16
    #pragma unroll
    for (int j = 0; j < 4; ++j) {
        bf16x8 bb[4];
        #pragma unroll
        for (int kk = 0; kk < 4; ++kk)
            bb[kk] = *(const bf16x8*)(bbase + (size_t)j * 16 * CIN + kk * 32);

        f32x4 acc[4];
        #pragma unroll
        for (int i = 0; i < 4; ++i) acc[i] = (f32x4){0.0f, 0.0f, 0.0f, 0.0f};
        #pragma unroll
        for (int kk = 0; kk < 4; ++kk)
            #pragma unroll
            for (int i = 0; i < 4; ++i)
                acc[i] = __builtin_amdgcn_mfma_f32_16x16x32_bf16(a[i][kk], bb[kk], acc[i], 0, 0, 0);

        // C/D layout: col(cell)=lane&15, row(o)=(lane>>4)*4+reg
        #pragma unroll
        for (int i = 0; i < 4; ++i) {
            int o = (w * 4 + i) * 16 + orow;
            ushort4 st;
            st.x = f2bf(acc[i][0]);
            st.y = f2bf(acc[i][1]);
            st.z = f2bf(acc[i][2]);
            st.w = f2bf(acc[i][3]);
            *(ushort4*)(&lds16[(j * 16 + l15) * LDSW16 + o]) = st;
        }
    }

    __syncthreads();  // lds16 + flat list visible

    // scatter: wave w handles points w, w+4, ... ; one float4 quarter-row per lane
    int nt = nflat; nt = nt < FLATCAP ? nt : FLATCAP;
    for (int k = w; k < nt; k += 4) {
        int pid = fpid[k];
        int c = fcell[k];
        ushort4 v = *(const ushort4*)(&lds16[c * LDSW16 + lane * 4]);
        float4 o4;
        o4.x = bf2f(v.x);
        o4.y = bf2f(v.y);
        o4.z = bf2f(v.z);
        o4.w = bf2f(v.w);
        *(float4*)(out + (size_t)pid * COUT + lane * 4) = o4;
    }
}

extern "C" void kernel_launch(void* const* d_in, const int* in_sizes, int n_in,
                              void* d_out, int out_size, void* d_ws, size_t ws_size,
                              hipStream_t stream)
{
    const float* feats = (const float*)d_in[0];
    const int*   idx   = (const int*)d_in[1];
    const float* nw    = (const float*)d_in[2];
    const float* nb    = (const float*)d_in[3];
    const float* lw    = (const float*)d_in[4];
    float* out = (float*)d_out;

    char* ws = (char*)d_ws;
    int* counts = (int*)ws;                                        // 0.56 MB
    int* plist  = (int*)(ws + (1u << 20));                         // 18 MB
    unsigned short* normed = (unsigned short*)(ws + (20u << 20));  // 36 MB bf16
    unsigned short* wb     = (unsigned short*)(ws + (60u << 20));  // 64 KB bf16

    hipMemsetAsync(counts, 0, (size_t)CELLS * 4, stream);
    build_kernel<<<NPTS / 256, 256, 0, stream>>>(idx, counts, plist, out + FEAT_OUT_ELEMS, out);
    cell_kernel<<<CELLS / 4, 256, 0, stream>>>(feats, counts, plist, nw, nb, normed);
    wcvt_kernel<<<COUT * CIN / 256, 256, 0, stream>>>(lw, wb);
    gemm_scatter_kernel<<<CELLS / 64, 256, 0, stream>>>(normed, wb, counts, plist, out);
}